// Round 9
// baseline (422.849 us; speedup 1.0000x reference)
//
#include <hip/hip_runtime.h>
#include <hip/hip_bf16.h>

// Problem constants (fixed by the reference)
#define N_NODES 10000
#define N_EDGES 160000
#define ETOT    (N_NODES + N_EDGES)
#define DIM     1024
#define NHEAD   4
#define DHEAD   256
#define NGRAPH  64
#define NEG_SLOPE 0.2f

typedef short  bf16x8 __attribute__((ext_vector_type(8)));
typedef float  f32x4  __attribute__((ext_vector_type(4)));
typedef unsigned short u16x4 __attribute__((ext_vector_type(4)));
typedef unsigned short u16x8 __attribute__((ext_vector_type(8)));

__device__ __forceinline__ unsigned short f2bf_rne(float v) {
    unsigned u = __builtin_bit_cast(unsigned, v);
    return (unsigned short)((u + 0x7fffu + ((u >> 16) & 1u)) >> 16);
}
__device__ __forceinline__ float bf2f(unsigned short b) {
    return __builtin_bit_cast(float, (unsigned)b << 16);
}
__device__ __forceinline__ float lrelu(float x) { return x > 0.f ? x : NEG_SLOPE * x; }

// ---------------------------------------------------------------------------
// TILED-FRAGMENT GLOBAL LAYOUT (round-8 fix for 15.5M ds_write conflicts):
// operand stored as 1 KB blocks, one per (16-row group g, 32-k tile kt), with
// lane slot l = (row&15) | (((k>>3)&3)<<4) holding 8 contiguous shorts:
//   off(row,k) = (row>>4)*16384 + (k>>5)*512 + ((k>>3)&3)*128 + (row&15)*8 + (k&7)
// gemm3 then stages via global_load_lds: src = block + lane*8 shorts
// (contiguous 1 KB, perfectly sorted) -> linear LDS dest = fragment order
// -> fragment reads at base+lane*16 are conflict-free. No ds_write at all.
// ---------------------------------------------------------------------------

// ---------------- split x into bf16 hi/lo (tiled layout) ----------------
__global__ __launch_bounds__(256) void prep_x(const float* __restrict__ x,
                                              unsigned short* __restrict__ xhi,
                                              unsigned short* __restrict__ xlo) {
    int i = blockIdx.x * 256 + threadIdx.x;     // i = row*128 + kseg (kseg = k>>3)
    if (i >= N_NODES * 128) return;
    int row = i >> 7, kseg = i & 127;
    const float* src = x + (size_t)row * DIM + kseg * 8;
    f32x4 v0 = *(const f32x4*)src;
    f32x4 v1 = *(const f32x4*)(src + 4);
    u16x8 hi, lo;
#pragma unroll
    for (int j = 0; j < 4; ++j) {
        unsigned short hb = f2bf_rne(v0[j]);
        hi[j] = hb; lo[j] = f2bf_rne(v0[j] - bf2f(hb));
    }
#pragma unroll
    for (int j = 0; j < 4; ++j) {
        unsigned short hb = f2bf_rne(v1[j]);
        hi[4 + j] = hb; lo[4 + j] = f2bf_rne(v1[j] - bf2f(hb));
    }
    size_t off = (size_t)(row >> 4) * 16384 + (kseg >> 2) * 512 + (kseg & 3) * 128 + (row & 15) * 8;
    *(u16x8*)(xhi + off) = hi;
    *(u16x8*)(xlo + off) = lo;
}

// ------ transpose + split W[2] (tiled layout over cols) + pipeline inits ------
__global__ __launch_bounds__(256) void prep_w(const float* __restrict__ W2,
                                              unsigned short* __restrict__ wthi,
                                              unsigned short* __restrict__ wtlo,
                                              float* __restrict__ es,
                                              float* __restrict__ ed,
                                              int* __restrict__ cnt,
                                              int* __restrict__ curs,
                                              int* __restrict__ gcnt,
                                              int* __restrict__ gbeg,
                                              int* __restrict__ gend) {
    __shared__ float tile[64][65];
    int bc = blockIdx.x;      // output-col tile
    int bk = blockIdx.y;      // k tile
    int t = threadIdx.x;

    // piggybacked inits (65536 threads >= all init ranges; completes before
    // any later kernel in the stream starts)
    int gid = (blockIdx.y * gridDim.x + blockIdx.x) * 256 + t;
    if (gid < NGRAPH) { gcnt[gid] = 0; gbeg[gid] = 0x7fffffff; gend[gid] = -1; }
    if (gid < N_NODES) { cnt[gid] = 1; curs[gid] = 0; }   // 1 = self loop
    if (gid < N_NODES * 4) { es[gid] = 0.f; ed[gid] = 0.f; }

    int tj = t & 63, ti = t >> 6;
#pragma unroll
    for (int u = 0; u < 16; ++u) {
        int r = u * 4 + ti;   // k-local
        tile[r][tj] = W2[(size_t)(bk * 64 + r) * DIM + bc * 64 + tj];
    }
    __syncthreads();
#pragma unroll
    for (int u = 0; u < 16; ++u) {
        int cr = u * 4 + ti;  // c-local
        float v = tile[tj][cr];   // = W2[bk*64+tj][bc*64+cr]
        unsigned short hb = f2bf_rne(v);
        float rres = v - bf2f(hb);
        int col = bc * 64 + cr;
        int k = bk * 64 + tj;
        size_t o = (size_t)(col >> 4) * 16384 + (k >> 5) * 512
                 + ((k >> 3) & 3) * 128 + (col & 15) * 8 + (k & 7);
        wthi[o] = hb;
        wtlo[o] = f2bf_rne(rres);
    }
}

// ---------------- 3-term split-bf16 MFMA GEMM + fused attention dots ----------------
// x @ W ~= xhi@Whi + xhi@Wlo + xlo@Whi  (fp32 accumulate)
#define BM 128
#define BN 128
#define BK 32
#define NROWT ((N_NODES + BM - 1) / BM)   // 79 row tiles
#define NCOLT (DIM / BN)                  // 8 col tiles

__global__ __launch_bounds__(256) void gemm3(const unsigned short* __restrict__ xhi,
                                             const unsigned short* __restrict__ xlo,
                                             const unsigned short* __restrict__ wthi,
                                             const unsigned short* __restrict__ wtlo,
                                             const float* __restrict__ asrc,
                                             const float* __restrict__ adst,
                                             unsigned short* __restrict__ hb,
                                             float* __restrict__ es,
                                             float* __restrict__ ed) {
    // XCD-grouping swizzle (round-robin id%8 -> XCD): the 8 col-tiles sharing
    // one A row-block run on ONE XCD -> A read once from HBM (FETCH ~53 MB).
    const int id = blockIdx.x;
    const int xcd = id & 7;
    const int br = xcd + 8 * (id >> 6);     // row tile
    const int bc = (id >> 3) & 7;           // col tile
    if (br >= NROWT) return;
    const int r0 = br * BM;
    const int c0 = bc * BN;

    __shared__ short lds[4][BM * BK];   // 0:Ahi 1:Alo 2:Bhi 3:Blo — 8 KB each
    const int t = threadIdx.x;
    const int lane = t & 63, wid = t >> 6;
    const int wm = wid >> 1, wn = wid & 1;

    // each wave stages its own buffer: wave 0:Ahi 1:Alo 2:Bhi 3:Blo
    const unsigned short* const srcs[4] = {xhi, xlo, wthi, wtlo};
    // tiled layout: block (g, kt) at shorts g*16384 + kt*512; lane slot at +lane*8
    const int g0 = ((wid < 2) ? r0 : c0) >> 4;
    const unsigned short* gsrc = srcs[wid] + (size_t)g0 * 16384 + (size_t)lane * 8;
    // OOB A-row-groups (last row tile, g>=625) read garbage inside ws (xlo/wthi
    // regions); those rows are never stored (row<N_NODES guards below).

    f32x4 acc[4][4];
#pragma unroll
    for (int mi = 0; mi < 4; ++mi)
#pragma unroll
        for (int ni = 0; ni < 4; ++ni) acc[mi][ni] = (f32x4){0.f, 0.f, 0.f, 0.f};

    for (int kt = 0; kt < DIM / BK; ++kt) {
        __syncthreads();   // previous iteration's fragment reads complete
#pragma unroll
        for (int j = 0; j < 8; ++j) {
            // subtile j: one contiguous 1 KB block, lane l -> byte l*16 (sorted)
            const unsigned short* g = gsrc + (size_t)j * 16384 + (size_t)kt * 512;
            __builtin_amdgcn_global_load_lds(
                (const __attribute__((address_space(1))) unsigned int*)g,
                (__attribute__((address_space(3))) unsigned int*)&lds[wid][j * 512],
                16, 0, 0);
        }
        __syncthreads();   // compiler drains vmcnt before barrier

        bf16x8 ahi[4], alo[4], bhi[4], blo[4];
#pragma unroll
        for (int mi = 0; mi < 4; ++mi) {
            int sub = wm * 4 + mi;          // A subtile index
            ahi[mi] = *(const bf16x8*)&lds[0][sub * 512 + lane * 8];
            alo[mi] = *(const bf16x8*)&lds[1][sub * 512 + lane * 8];
        }
#pragma unroll
        for (int ni = 0; ni < 4; ++ni) {
            int sub = wn * 4 + ni;          // B subtile index
            bhi[ni] = *(const bf16x8*)&lds[2][sub * 512 + lane * 8];
            blo[ni] = *(const bf16x8*)&lds[3][sub * 512 + lane * 8];
        }
#pragma unroll
        for (int mi = 0; mi < 4; ++mi)
#pragma unroll
            for (int ni = 0; ni < 4; ++ni) {
                f32x4 c = acc[mi][ni];
                c = __builtin_amdgcn_mfma_f32_16x16x32_bf16(ahi[mi], bhi[ni], c, 0, 0, 0);
                c = __builtin_amdgcn_mfma_f32_16x16x32_bf16(ahi[mi], blo[ni], c, 0, 0, 0);
                c = __builtin_amdgcn_mfma_f32_16x16x32_bf16(alo[mi], bhi[ni], c, 0, 0, 0);
                acc[mi][ni] = c;
            }
    }

    // epilogue 1: bf16 store (C/D map: col=lane&15, row=(lane>>4)*4+v  [m89/m91])
#pragma unroll
    for (int mi = 0; mi < 4; ++mi)
#pragma unroll
        for (int ni = 0; ni < 4; ++ni)
#pragma unroll
            for (int v = 0; v < 4; ++v) {
                int row = r0 + wm * 64 + mi * 16 + ((lane >> 4) << 2) + v;
                if (row < N_NODES) {
                    int col = c0 + wn * 64 + ni * 16 + (lane & 15);
                    hb[(size_t)row * DIM + col] = f2bf_rne(acc[mi][ni][v]);
                }
            }

    // epilogue 2: fused attention dots — partial es/ed from fp32 acc.
    // This block's 128 cols lie within ONE head (c0 % 256 in {0,128}).
    const int head = c0 >> 8;
    float as_c[4], ad_c[4];
#pragma unroll
    for (int ni = 0; ni < 4; ++ni) {
        int col = c0 + wn * 64 + ni * 16 + (lane & 15);
        as_c[ni] = asrc[col];
        ad_c[ni] = adst[col];
    }
#pragma unroll
    for (int mi = 0; mi < 4; ++mi)
#pragma unroll
        for (int v = 0; v < 4; ++v) {
            float pe = 0.f, pd = 0.f;
#pragma unroll
            for (int ni = 0; ni < 4; ++ni) {
                float a = acc[mi][ni][v];
                pe += a * as_c[ni];
                pd += a * ad_c[ni];
            }
            // reduce over the 16 cols (lane&15 axis); row is uniform per group
#pragma unroll
            for (int d = 1; d < 16; d <<= 1) {
                pe += __shfl_xor(pe, d);
                pd += __shfl_xor(pd, d);
            }
            int row = r0 + wm * 64 + mi * 16 + ((lane >> 4) << 2) + v;
            if ((lane & 15) == 0 && row < N_NODES) {
                atomicAdd(es + row * 4 + head, pe);
                atomicAdd(ed + row * 4 + head, pd);
            }
        }
}

// ---------------- fused edge histogram + per-graph ranges ----------------
__global__ void graph_k(const int* __restrict__ dst, const int* __restrict__ batch,
                        int* cnt, int* gcnt, int* gbeg, int* gend) {
    int e = blockIdx.x * 256 + threadIdx.x;
    if (e < N_EDGES) atomicAdd(cnt + dst[e], 1);
    if (e < N_NODES) {
        int b = batch[e];
        atomicAdd(gcnt + b, 1);
        atomicMin(gbeg + b, e);
        atomicMax(gend + b, e);
    }
}

// shfl-based scan (wave-level, few barriers)
__global__ __launch_bounds__(1024) void scan_k(const int* __restrict__ cnt, int* __restrict__ off) {
    __shared__ int wsh[16];
    __shared__ int tot_s;
    int t = threadIdx.x, lane = t & 63, wv = t >> 6;
    int running = 0;
    for (int c0 = 0; c0 < N_NODES; c0 += 1024) {
        int i = c0 + t;
        int v = (i < N_NODES) ? cnt[i] : 0;
        int s = v;
#pragma unroll
        for (int d = 1; d < 64; d <<= 1) {
            int y = __shfl_up(s, d);
            if (lane >= d) s += y;
        }
        if (lane == 63) wsh[wv] = s;
        __syncthreads();
        if (wv == 0) {
            int wsv = (lane < 16) ? wsh[lane] : 0;
            int e = wsv;
#pragma unroll
            for (int d = 1; d < 16; d <<= 1) {
                int y = __shfl_up(e, d);
                if (lane >= d) e += y;
            }
            if (lane < 16) wsh[lane] = e - wsv;   // exclusive wave prefix
            if (lane == 15) tot_s = e;            // chunk total
        }
        __syncthreads();
        if (i < N_NODES) off[i] = running + wsh[wv] + s - v;
        running += tot_s;
    }
}

__global__ void bucket_k(const int* __restrict__ src, const int* __restrict__ dst,
                         const int* __restrict__ off, int* cursor, int* bucket) {
    int e = blockIdx.x * 256 + threadIdx.x;
    if (e >= ETOT) return;
    int d = (e < N_EDGES) ? dst[e] : (e - N_EDGES);
    int pos = atomicAdd(cursor + d, 1);
    bucket[off[d] + pos] = e;
}

// ---------------- fused softmax + aggregate + bias + relu -> out[n] ----------------
#define HCAP 192
__global__ __launch_bounds__(256) void aggregate_k(const unsigned short* __restrict__ hb,
                                                   const float* __restrict__ es,
                                                   const float* __restrict__ ed,
                                                   const int* __restrict__ src,
                                                   const int* __restrict__ cnt,
                                                   const int* __restrict__ off,
                                                   const int* __restrict__ bucket,
                                                   const float* __restrict__ b2,
                                                   float* __restrict__ out) {
    int n = blockIdx.x, t = threadIdx.x;
    int deg = cnt[n], base = off[n];
    f32x4 edn = *(const f32x4*)(ed + (size_t)n * 4);
    __shared__ int  s_src[HCAP];
    __shared__ f32x4 s_e[HCAP];
    __shared__ f32x4 wred[4];

    // phase 1: edge scores + per-head max
    f32x4 m4 = {-3e38f, -3e38f, -3e38f, -3e38f};
    for (int i = t; i < deg; i += 256) {
        int eid = bucket[base + i];
        int s = (eid < N_EDGES) ? src[eid] : (eid - N_EDGES);
        f32x4 e4 = *(const f32x4*)(es + (size_t)s * 4);
        e4.x = lrelu(e4.x + edn.x); e4.y = lrelu(e4.y + edn.y);
        e4.z = lrelu(e4.z + edn.z); e4.w = lrelu(e4.w + edn.w);
        if (i < HCAP) { s_src[i] = s; s_e[i] = e4; }
        m4.x = fmaxf(m4.x, e4.x); m4.y = fmaxf(m4.y, e4.y);
        m4.z = fmaxf(m4.z, e4.z); m4.w = fmaxf(m4.w, e4.w);
    }
#pragma unroll
    for (int d = 1; d < 64; d <<= 1) {
        m4.x = fmaxf(m4.x, __shfl_xor(m4.x, d));
        m4.y = fmaxf(m4.y, __shfl_xor(m4.y, d));
        m4.z = fmaxf(m4.z, __shfl_xor(m4.z, d));
        m4.w = fmaxf(m4.w, __shfl_xor(m4.w, d));
    }
    if ((t & 63) == 0) wred[t >> 6] = m4;
    __syncthreads();
    f32x4 mm = wred[0];
#pragma unroll
    for (int w = 1; w < 4; ++w) {
        mm.x = fmaxf(mm.x, wred[w].x); mm.y = fmaxf(mm.y, wred[w].y);
        mm.z = fmaxf(mm.z, wred[w].z); mm.w = fmaxf(mm.w, wred[w].w);
    }
    int hd = t >> 6;
    float mh = hd == 0 ? mm.x : hd == 1 ? mm.y : hd == 2 ? mm.z : mm.w;

    // phase 2: weighted accumulate over bf16 h rows (thread t owns cols [t*4, t*4+4))
    f32x4 acc = {0.f, 0.f, 0.f, 0.f};
    float sump = 0.f;
    for (int i = 0; i < deg; ++i) {
        int s;
        f32x4 e4;
        if (i < HCAP) { s = s_src[i]; e4 = s_e[i]; }
        else {
            int eid = bucket[base + i];
            s = (eid < N_EDGES) ? src[eid] : (eid - N_EDGES);
            e4 = *(const f32x4*)(es + (size_t)s * 4);
            e4.x = lrelu(e4.x + edn.x); e4.y = lrelu(e4.y + edn.y);
            e4.z = lrelu(e4.z + edn.z); e4.w = lrelu(e4.w + edn.w);
        }
        float eh = hd == 0 ? e4.x : hd == 1 ? e4.y : hd == 2 ? e4.z : e4.w;
        float p = expf(eh - mh);
        sump += p;
        u16x4 q = *(const u16x4*)(hb + (size_t)s * DIM + t * 4);
        f32x4 hv = {bf2f(q[0]), bf2f(q[1]), bf2f(q[2]), bf2f(q[3])};
        acc += p * hv;
    }
    float inv = 1.0f / (sump + 1e-16f);
    f32x4 bb = *(const f32x4*)(b2 + t * 4);
    f32x4 r = acc * inv + bb;
    r.x = fmaxf(r.x, 0.f); r.y = fmaxf(r.y, 0.f);
    r.z = fmaxf(r.z, 0.f); r.w = fmaxf(r.w, 0.f);
    *(f32x4*)(out + (size_t)n * DIM + t * 4) = r;   // plain coalesced store, no atomics
}

// ---------------- per-graph pooling (no atomics: batch is sorted) ----------------
__global__ __launch_bounds__(256) void pool_k(const float* __restrict__ out,
                                              const int* __restrict__ gbeg,
                                              const int* __restrict__ gend,
                                              float* __restrict__ pooled) {
    int g = blockIdx.x, c = blockIdx.y, t = threadIdx.x;
    int col = c * 256 + t;
    int b0 = gbeg[g], b1 = gend[g];
    float acc = 0.f;
    for (int n = b0; n <= b1; ++n) acc += out[(size_t)n * DIM + col];
    pooled[(size_t)g * DIM + col] = acc;   // sum; final_k divides by count
}

// ---------------- final: (pooled/cnt) @ Wr + br ----------------
__global__ __launch_bounds__(256) void final_k(const float* __restrict__ pooled,
                                               const int* __restrict__ gcnt,
                                               const float* __restrict__ Wr,
                                               const float* __restrict__ br,
                                               float* __restrict__ out) {
    int g = blockIdx.x, t = threadIdx.x;
    float s0 = 0.f, s1 = 0.f;
    for (int d = t; d < DIM; d += 256) {
        float v = pooled[(size_t)g * DIM + d];
        s0 += v * Wr[d * 2];
        s1 += v * Wr[d * 2 + 1];
    }
    __shared__ float r0[256], r1[256];
    r0[t] = s0; r1[t] = s1;
    __syncthreads();
    for (int st = 128; st > 0; st >>= 1) {
        if (t < st) { r0[t] += r0[t + st]; r1[t] += r1[t + st]; }
        __syncthreads();
    }
    if (t == 0) {
        float c = fmaxf((float)gcnt[g], 1.f);
        out[g * 2 + 0] = r0[0] / c + br[0];
        out[g * 2 + 1] = r1[0] / c + br[1];
    }
}

// ---------------- launch ----------------
extern "C" void kernel_launch(void* const* d_in, const int* in_sizes, int n_in,
                              void* d_out, int out_size, void* d_ws, size_t ws_size,
                              hipStream_t stream) {
    (void)in_sizes; (void)n_in; (void)out_size; (void)ws_size;
    const float* x     = (const float*)d_in[0];
    const int*   ei    = (const int*)d_in[1];
    const int*   batch = (const int*)d_in[2];
    const float* W     = (const float*)d_in[3];
    const float* a_src = (const float*)d_in[4];
    const float* a_dst = (const float*)d_in[5];
    const float* b     = (const float*)d_in[6];
    const float* Wr    = (const float*)d_in[7];
    const float* br    = (const float*)d_in[8];

    // Reference: each block reads the ORIGINAL x -> only block i=2 matters.
    const float* W2    = W + (size_t)2 * DIM * DIM;
    const float* asrc2 = a_src + 2 * NHEAD * DHEAD;
    const float* adst2 = a_dst + 2 * NHEAD * DHEAD;
    const float* b2    = b + 2 * DIM;
    const int* srcI = ei;
    const int* dstI = ei + N_EDGES;

    char* wsp = (char*)d_ws;
    size_t o = 0;
    auto alloc = [&](size_t bytes) -> char* {
        char* p = wsp + o;
        o = (o + bytes + 255) & ~(size_t)255;
        return p;
    };
    unsigned short* xhi  = (unsigned short*)alloc((size_t)N_NODES * DIM * 2);  // 20.48 MB (tiled)
    unsigned short* xlo  = (unsigned short*)alloc((size_t)N_NODES * DIM * 2);  // 20.48 MB (tiled)
    unsigned short* wthi = (unsigned short*)alloc((size_t)DIM * DIM * 2);      // tiled
    unsigned short* wtlo = (unsigned short*)alloc((size_t)DIM * DIM * 2);      // tiled
    unsigned short* hb   = (unsigned short*)alloc((size_t)N_NODES * DIM * 2);  // h in bf16, row-major
    float* es   = (float*)alloc((size_t)N_NODES * 4 * 4);
    float* ed   = (float*)alloc((size_t)N_NODES * 4 * 4);
    int*   cnt  = (int*)alloc((size_t)N_NODES * 4);
    int*   offs = (int*)alloc((size_t)N_NODES * 4);
    int*   curs = (int*)alloc((size_t)N_NODES * 4);
    int*   bkt  = (int*)alloc((size_t)ETOT * 4);
    float* pooled = (float*)alloc((size_t)NGRAPH * DIM * 4);
    int*   gcnt   = (int*)alloc(NGRAPH * 4);
    int*   gbeg   = (int*)alloc(NGRAPH * 4);
    int*   gend   = (int*)alloc(NGRAPH * 4);
    // out[n] (41 MB f32) aliases xhi+xlo — dead after gemm3.
    float* outn = (float*)xhi;

    prep_x<<<(N_NODES * 128 + 255) / 256, 256, 0, stream>>>(x, xhi, xlo);
    prep_w<<<dim3(16, 16), 256, 0, stream>>>(W2, wthi, wtlo, es, ed, cnt, curs, gcnt, gbeg, gend);
    gemm3<<<((NROWT + 7) / 8) * 8 * NCOLT, 256, 0, stream>>>(xhi, xlo, wthi, wtlo,
                                                             asrc2, adst2, hb, es, ed);
    graph_k<<<(N_EDGES + 255) / 256, 256, 0, stream>>>(dstI, batch, cnt, gcnt, gbeg, gend);
    scan_k<<<1, 1024, 0, stream>>>(cnt, offs);
    bucket_k<<<(ETOT + 255) / 256, 256, 0, stream>>>(srcI, dstI, offs, curs, bkt);

    aggregate_k<<<N_NODES, 256, 0, stream>>>(hb, es, ed, srcI, cnt, offs, bkt, b2, outn);
    pool_k<<<dim3(NGRAPH, 4), 256, 0, stream>>>(outn, gbeg, gend, pooled);
    final_k<<<NGRAPH, 256, 0, stream>>>(pooled, gcnt, Wr, br, (float*)d_out);
}

// Round 15
// 408.335 us; speedup vs baseline: 1.0355x; 1.0355x over previous
//
#include <hip/hip_runtime.h>
#include <hip/hip_bf16.h>

// Problem constants (fixed by the reference)
#define N_NODES 10000
#define N_EDGES 160000
#define ETOT    (N_NODES + N_EDGES)
#define DIM     1024
#define NHEAD   4
#define DHEAD   256
#define NGRAPH  64
#define NEG_SLOPE 0.2f

typedef short  bf16x8 __attribute__((ext_vector_type(8)));
typedef float  f32x4  __attribute__((ext_vector_type(4)));
typedef unsigned short u16x4 __attribute__((ext_vector_type(4)));
typedef unsigned short u16x8 __attribute__((ext_vector_type(8)));

__device__ __forceinline__ unsigned short f2bf_rne(float v) {
    unsigned u = __builtin_bit_cast(unsigned, v);
    return (unsigned short)((u + 0x7fffu + ((u >> 16) & 1u)) >> 16);
}
__device__ __forceinline__ float bf2f(unsigned short b) {
    return __builtin_bit_cast(float, (unsigned)b << 16);
}
__device__ __forceinline__ float lrelu(float x) { return x > 0.f ? x : NEG_SLOPE * x; }

// ---------------------------------------------------------------------------
// REGIME LESSON (rounds 5/7/9 A/B/C): gemm3 is a 2-barrier-per-K-step loop ->
// critical path is stage+vmcnt(0)drain+barrier. LDS bank conflicts (5.2M) and
// L2 over-fetch (168 MB) are HIDDEN in this regime: fixing them (r7: scatter
// ds_write 15.5M conflicts, 95us; r9: tiled-global 0 conflicts, 105us) only
// added cost. r5's structure (global_load_lds, k-major LDS, natural 2D grid
// with id%8==bc XCD affinity) measured fastest: 82us. This file returns to it
// and keeps only the staging-independent wins (fused dots, merged dispatches).
// ---------------------------------------------------------------------------

// ------ transpose + split W[2] -> row-major W^T (K-contig) + pipeline inits ------
__global__ __launch_bounds__(256) void prep_w(const float* __restrict__ W2,
                                              unsigned short* __restrict__ wthi,
                                              unsigned short* __restrict__ wtlo,
                                              float* __restrict__ es,
                                              float* __restrict__ ed,
                                              int* __restrict__ cnt,
                                              int* __restrict__ curs,
                                              int* __restrict__ gcnt,
                                              int* __restrict__ gbeg,
                                              int* __restrict__ gend) {
    __shared__ float tile[64][65];
    int bc = blockIdx.x;      // output-col tile
    int bk = blockIdx.y;      // k tile
    int t = threadIdx.x;

    // piggybacked inits (256 blocks x 256 thr = 65536 >= all init ranges;
    // stream order guarantees completion before later kernels)
    int gid = (blockIdx.y * gridDim.x + blockIdx.x) * 256 + t;
    if (gid < NGRAPH) { gcnt[gid] = 0; gbeg[gid] = 0x7fffffff; gend[gid] = -1; }
    if (gid < N_NODES) { cnt[gid] = 1; curs[gid] = 0; }   // 1 = self loop
    if (gid < N_NODES * 4) { es[gid] = 0.f; ed[gid] = 0.f; }

    int tj = t & 63, ti = t >> 6;
#pragma unroll
    for (int u = 0; u < 16; ++u) {
        int r = u * 4 + ti;   // k-local
        tile[r][tj] = W2[(size_t)(bk * 64 + r) * DIM + bc * 64 + tj];
    }
    __syncthreads();
#pragma unroll
    for (int u = 0; u < 16; ++u) {
        int cr = u * 4 + ti;  // c-local
        float v = tile[tj][cr];   // = W2[bk*64+tj][bc*64+cr]
        unsigned short hb = f2bf_rne(v);
        float rres = v - bf2f(hb);
        size_t o = (size_t)(bc * 64 + cr) * DIM + bk * 64 + tj;   // W^T row-major
        wthi[o] = hb;
        wtlo[o] = f2bf_rne(rres);
    }
}

// ------ split x into bf16 hi/lo (row-major) + edge hist + graph ranges ------
#define XBLK (N_NODES * DIM / 4 / 256)   // 10000 blocks for x
__global__ __launch_bounds__(256) void prep_xg(const float* __restrict__ x,
                                               unsigned short* __restrict__ xhi,
                                               unsigned short* __restrict__ xlo,
                                               const int* __restrict__ dst,
                                               const int* __restrict__ batch,
                                               int* __restrict__ cnt,
                                               int* __restrict__ gcnt,
                                               int* __restrict__ gbeg,
                                               int* __restrict__ gend) {
    int bid = blockIdx.x;
    if (bid < XBLK) {
        int i = bid * 256 + threadIdx.x;       // group of 4 floats, always in range
        f32x4 v = *(const f32x4*)(x + (size_t)i * 4);
        u16x4 hi, lo;
#pragma unroll
        for (int j = 0; j < 4; ++j) {
            unsigned short hb = f2bf_rne(v[j]);
            float r = v[j] - bf2f(hb);
            hi[j] = hb;
            lo[j] = f2bf_rne(r);
        }
        *(u16x4*)(xhi + (size_t)i * 4) = hi;
        *(u16x4*)(xlo + (size_t)i * 4) = lo;
    } else {
        int e = (bid - XBLK) * 256 + threadIdx.x;
        if (e < N_EDGES) atomicAdd(cnt + dst[e], 1);
        if (e < N_NODES) {
            int b = batch[e];
            atomicAdd(gcnt + b, 1);
            atomicMin(gbeg + b, e);
            atomicMax(gend + b, e);
        }
    }
}

// ---------------- 3-term split-bf16 MFMA GEMM + fused attention dots ----------------
// x @ W ~= xhi@Whi + xhi@Wlo + xlo@Whi  (fp32 accumulate)
#define BM 128
#define BN 128
#define BK 32
#define NROWT ((N_NODES + BM - 1) / BM)   // 79 row tiles
#define NCOLT (DIM / BN)                  // 8 col tiles

__global__ __launch_bounds__(256) void gemm3(const unsigned short* __restrict__ xhi,
                                             const unsigned short* __restrict__ xlo,
                                             const unsigned short* __restrict__ wthi,
                                             const unsigned short* __restrict__ wtlo,
                                             const float* __restrict__ asrc,
                                             const float* __restrict__ adst,
                                             unsigned short* __restrict__ hb,
                                             float* __restrict__ es,
                                             float* __restrict__ ed) {
    // natural 2D grid: linear id = by*8+bx -> id%8 == bx == col-tile, so under
    // round-robin XCD placement each col-tile's B slice pins to one XCD's L2.
    const int r0 = blockIdx.y * BM;
    const int c0 = blockIdx.x * BN;

    __shared__ short lds[4][BM * BK];   // 0:Ahi 1:Alo 2:Bhi 3:Blo — 8 KB each
    const int t = threadIdx.x;
    const int lane = t & 63, wid = t >> 6;
    const int wm = wid >> 1, wn = wid & 1;

    // each wave stages its own buffer: wave 0:Ahi 1:Alo 2:Bhi 3:Blo
    const unsigned short* const srcs[4] = {xhi, xlo, wthi, wtlo};
    const unsigned short* wbase = srcs[wid];
    const int rowb = (wid < 2) ? r0 : c0;
    // OOB A-rows (last row tile) read garbage inside ws (xlo/wthi regions);
    // those rows are never stored (row<N_NODES guards below).

    f32x4 acc[4][4];
#pragma unroll
    for (int mi = 0; mi < 4; ++mi)
#pragma unroll
        for (int ni = 0; ni < 4; ++ni) acc[mi][ni] = (f32x4){0.f, 0.f, 0.f, 0.f};

    const int rL = lane & 15;
    const int koff = (lane >> 4) * 8;   // element offset into K (8 bf16 = 16 B)

    for (int k0 = 0; k0 < DIM; k0 += BK) {
        __syncthreads();   // previous iteration's fragment reads done before overwrite
#pragma unroll
        for (int j = 0; j < 8; ++j) {
            // chunk j: rows j*16 + (lane>>2), 4 x 16 B segments per row (sorted)
            const unsigned short* g = wbase
                + (size_t)(rowb + j * 16 + (lane >> 2)) * DIM + k0 + (lane & 3) * 8;
            __builtin_amdgcn_global_load_lds(
                (const __attribute__((address_space(1))) unsigned int*)g,
                (__attribute__((address_space(3))) unsigned int*)&lds[wid][j * 512],
                16, 0, 0);
        }
        __syncthreads();   // compiler drains vmcnt before barrier

        bf16x8 ahi[4], alo[4], bhi[4], blo[4];
#pragma unroll
        for (int mi = 0; mi < 4; ++mi) {
            int row = wm * 64 + mi * 16 + rL;
            ahi[mi] = *(const bf16x8*)&lds[0][row * BK + koff];
            alo[mi] = *(const bf16x8*)&lds[1][row * BK + koff];
        }
#pragma unroll
        for (int ni = 0; ni < 4; ++ni) {
            int row = wn * 64 + ni * 16 + rL;
            bhi[ni] = *(const bf16x8*)&lds[2][row * BK + koff];
            blo[ni] = *(const bf16x8*)&lds[3][row * BK + koff];
        }
#pragma unroll
        for (int mi = 0; mi < 4; ++mi)
#pragma unroll
            for (int ni = 0; ni < 4; ++ni) {
                f32x4 c = acc[mi][ni];
                c = __builtin_amdgcn_mfma_f32_16x16x32_bf16(ahi[mi], bhi[ni], c, 0, 0, 0);
                c = __builtin_amdgcn_mfma_f32_16x16x32_bf16(ahi[mi], blo[ni], c, 0, 0, 0);
                c = __builtin_amdgcn_mfma_f32_16x16x32_bf16(alo[mi], bhi[ni], c, 0, 0, 0);
                acc[mi][ni] = c;
            }
    }

    // epilogue 1: bf16 store (C/D map: col=lane&15, row=(lane>>4)*4+v  [m89/m91])
#pragma unroll
    for (int mi = 0; mi < 4; ++mi)
#pragma unroll
        for (int ni = 0; ni < 4; ++ni)
#pragma unroll
            for (int v = 0; v < 4; ++v) {
                int row = r0 + wm * 64 + mi * 16 + ((lane >> 4) << 2) + v;
                if (row < N_NODES) {
                    int col = c0 + wn * 64 + ni * 16 + (lane & 15);
                    hb[(size_t)row * DIM + col] = f2bf_rne(acc[mi][ni][v]);
                }
            }

    // epilogue 2: fused attention dots — partial es/ed from fp32 acc.
    // This block's 128 cols lie within ONE head (c0 % 256 in {0,128}).
    const int head = c0 >> 8;
    float as_c[4], ad_c[4];
#pragma unroll
    for (int ni = 0; ni < 4; ++ni) {
        int col = c0 + wn * 64 + ni * 16 + (lane & 15);
        as_c[ni] = asrc[col];
        ad_c[ni] = adst[col];
    }
#pragma unroll
    for (int mi = 0; mi < 4; ++mi)
#pragma unroll
        for (int v = 0; v < 4; ++v) {
            float pe = 0.f, pd = 0.f;
#pragma unroll
            for (int ni = 0; ni < 4; ++ni) {
                float a = acc[mi][ni][v];
                pe += a * as_c[ni];
                pd += a * ad_c[ni];
            }
            // reduce over the 16 cols (lane&15 axis); row is uniform per group
#pragma unroll
            for (int d = 1; d < 16; d <<= 1) {
                pe += __shfl_xor(pe, d);
                pd += __shfl_xor(pd, d);
            }
            int row = r0 + wm * 64 + mi * 16 + ((lane >> 4) << 2) + v;
            if ((lane & 15) == 0 && row < N_NODES) {
                atomicAdd(es + row * 4 + head, pe);
                atomicAdd(ed + row * 4 + head, pd);
            }
        }
}

// shfl-based scan (wave-level, few barriers)
__global__ __launch_bounds__(1024) void scan_k(const int* __restrict__ cnt, int* __restrict__ off) {
    __shared__ int wsh[16];
    __shared__ int tot_s;
    int t = threadIdx.x, lane = t & 63, wv = t >> 6;
    int running = 0;
    for (int c0 = 0; c0 < N_NODES; c0 += 1024) {
        int i = c0 + t;
        int v = (i < N_NODES) ? cnt[i] : 0;
        int s = v;
#pragma unroll
        for (int d = 1; d < 64; d <<= 1) {
            int y = __shfl_up(s, d);
            if (lane >= d) s += y;
        }
        if (lane == 63) wsh[wv] = s;
        __syncthreads();
        if (wv == 0) {
            int wsv = (lane < 16) ? wsh[lane] : 0;
            int e = wsv;
#pragma unroll
            for (int d = 1; d < 16; d <<= 1) {
                int y = __shfl_up(e, d);
                if (lane >= d) e += y;
            }
            if (lane < 16) wsh[lane] = e - wsv;   // exclusive wave prefix
            if (lane == 15) tot_s = e;            // chunk total
        }
        __syncthreads();
        if (i < N_NODES) off[i] = running + wsh[wv] + s - v;
        running += tot_s;
    }
}

__global__ void bucket_k(const int* __restrict__ src, const int* __restrict__ dst,
                         const int* __restrict__ off, int* cursor, int* bucket) {
    int e = blockIdx.x * 256 + threadIdx.x;
    if (e >= ETOT) return;
    int d = (e < N_EDGES) ? dst[e] : (e - N_EDGES);
    int pos = atomicAdd(cursor + d, 1);
    bucket[off[d] + pos] = e;
}

// ---------------- fused softmax + aggregate + bias + relu -> out[n] ----------------
#define HCAP 192
__global__ __launch_bounds__(256) void aggregate_k(const unsigned short* __restrict__ hb,
                                                   const float* __restrict__ es,
                                                   const float* __restrict__ ed,
                                                   const int* __restrict__ src,
                                                   const int* __restrict__ cnt,
                                                   const int* __restrict__ off,
                                                   const int* __restrict__ bucket,
                                                   const float* __restrict__ b2,
                                                   float* __restrict__ out) {
    int n = blockIdx.x, t = threadIdx.x;
    int deg = cnt[n], base = off[n];
    f32x4 edn = *(const f32x4*)(ed + (size_t)n * 4);
    __shared__ int  s_src[HCAP];
    __shared__ f32x4 s_e[HCAP];
    __shared__ f32x4 wred[4];

    // phase 1: edge scores + per-head max
    f32x4 m4 = {-3e38f, -3e38f, -3e38f, -3e38f};
    for (int i = t; i < deg; i += 256) {
        int eid = bucket[base + i];
        int s = (eid < N_EDGES) ? src[eid] : (eid - N_EDGES);
        f32x4 e4 = *(const f32x4*)(es + (size_t)s * 4);
        e4.x = lrelu(e4.x + edn.x); e4.y = lrelu(e4.y + edn.y);
        e4.z = lrelu(e4.z + edn.z); e4.w = lrelu(e4.w + edn.w);
        if (i < HCAP) { s_src[i] = s; s_e[i] = e4; }
        m4.x = fmaxf(m4.x, e4.x); m4.y = fmaxf(m4.y, e4.y);
        m4.z = fmaxf(m4.z, e4.z); m4.w = fmaxf(m4.w, e4.w);
    }
#pragma unroll
    for (int d = 1; d < 64; d <<= 1) {
        m4.x = fmaxf(m4.x, __shfl_xor(m4.x, d));
        m4.y = fmaxf(m4.y, __shfl_xor(m4.y, d));
        m4.z = fmaxf(m4.z, __shfl_xor(m4.z, d));
        m4.w = fmaxf(m4.w, __shfl_xor(m4.w, d));
    }
    if ((t & 63) == 0) wred[t >> 6] = m4;
    __syncthreads();
    f32x4 mm = wred[0];
#pragma unroll
    for (int w = 1; w < 4; ++w) {
        mm.x = fmaxf(mm.x, wred[w].x); mm.y = fmaxf(mm.y, wred[w].y);
        mm.z = fmaxf(mm.z, wred[w].z); mm.w = fmaxf(mm.w, wred[w].w);
    }
    int hd = t >> 6;
    float mh = hd == 0 ? mm.x : hd == 1 ? mm.y : hd == 2 ? mm.z : mm.w;

    // phase 2: weighted accumulate over bf16 h rows (thread t owns cols [t*4, t*4+4))
    f32x4 acc = {0.f, 0.f, 0.f, 0.f};
    float sump = 0.f;
    for (int i = 0; i < deg; ++i) {
        int s;
        f32x4 e4;
        if (i < HCAP) { s = s_src[i]; e4 = s_e[i]; }
        else {
            int eid = bucket[base + i];
            s = (eid < N_EDGES) ? src[eid] : (eid - N_EDGES);
            e4 = *(const f32x4*)(es + (size_t)s * 4);
            e4.x = lrelu(e4.x + edn.x); e4.y = lrelu(e4.y + edn.y);
            e4.z = lrelu(e4.z + edn.z); e4.w = lrelu(e4.w + edn.w);
        }
        float eh = hd == 0 ? e4.x : hd == 1 ? e4.y : hd == 2 ? e4.z : e4.w;
        float p = expf(eh - mh);
        sump += p;
        u16x4 q = *(const u16x4*)(hb + (size_t)s * DIM + t * 4);
        f32x4 hv = {bf2f(q[0]), bf2f(q[1]), bf2f(q[2]), bf2f(q[3])};
        acc += p * hv;
    }
    float inv = 1.0f / (sump + 1e-16f);
    f32x4 bb = *(const f32x4*)(b2 + t * 4);
    f32x4 r = acc * inv + bb;
    r.x = fmaxf(r.x, 0.f); r.y = fmaxf(r.y, 0.f);
    r.z = fmaxf(r.z, 0.f); r.w = fmaxf(r.w, 0.f);
    *(f32x4*)(out + (size_t)n * DIM + t * 4) = r;   // plain coalesced store, no atomics
}

// ------ merged pool + final: (mean over graph) @ Wr + br  (no atomics) ------
__global__ __launch_bounds__(256) void poolfinal_k(const float* __restrict__ outn,
                                                   const int* __restrict__ gcnt,
                                                   const int* __restrict__ gbeg,
                                                   const int* __restrict__ gend,
                                                   const float* __restrict__ Wr,
                                                   const float* __restrict__ br,
                                                   float* __restrict__ out) {
    int g = blockIdx.x, t = threadIdx.x;
    int b0 = gbeg[g], b1 = gend[g];
    f32x4 acc = {0.f, 0.f, 0.f, 0.f};
    for (int n = b0; n <= b1; ++n)
        acc += *(const f32x4*)(outn + (size_t)n * DIM + t * 4);
    int c4 = t * 4;
    float s0 = acc.x * Wr[c4 * 2]     + acc.y * Wr[(c4 + 1) * 2]
             + acc.z * Wr[(c4 + 2) * 2] + acc.w * Wr[(c4 + 3) * 2];
    float s1 = acc.x * Wr[c4 * 2 + 1]     + acc.y * Wr[(c4 + 1) * 2 + 1]
             + acc.z * Wr[(c4 + 2) * 2 + 1] + acc.w * Wr[(c4 + 3) * 2 + 1];
    __shared__ float r0s[256], r1s[256];
    r0s[t] = s0; r1s[t] = s1;
    __syncthreads();
    for (int st = 128; st > 0; st >>= 1) {
        if (t < st) { r0s[t] += r0s[t + st]; r1s[t] += r1s[t + st]; }
        __syncthreads();
    }
    if (t == 0) {
        float c = fmaxf((float)gcnt[g], 1.f);
        out[g * 2 + 0] = r0s[0] / c + br[0];
        out[g * 2 + 1] = r1s[0] / c + br[1];
    }
}

// ---------------- launch ----------------
extern "C" void kernel_launch(void* const* d_in, const int* in_sizes, int n_in,
                              void* d_out, int out_size, void* d_ws, size_t ws_size,
                              hipStream_t stream) {
    (void)in_sizes; (void)n_in; (void)out_size; (void)ws_size;
    const float* x     = (const float*)d_in[0];
    const int*   ei    = (const int*)d_in[1];
    const int*   batch = (const int*)d_in[2];
    const float* W     = (const float*)d_in[3];
    const float* a_src = (const float*)d_in[4];
    const float* a_dst = (const float*)d_in[5];
    const float* b     = (const float*)d_in[6];
    const float* Wr    = (const float*)d_in[7];
    const float* br    = (const float*)d_in[8];

    // Reference: each block reads the ORIGINAL x -> only block i=2 matters.
    const float* W2    = W + (size_t)2 * DIM * DIM;
    const float* asrc2 = a_src + 2 * NHEAD * DHEAD;
    const float* adst2 = a_dst + 2 * NHEAD * DHEAD;
    const float* b2    = b + 2 * DIM;
    const int* srcI = ei;
    const int* dstI = ei + N_EDGES;

    char* wsp = (char*)d_ws;
    size_t o = 0;
    auto alloc = [&](size_t bytes) -> char* {
        char* p = wsp + o;
        o = (o + bytes + 255) & ~(size_t)255;
        return p;
    };
    unsigned short* xhi  = (unsigned short*)alloc((size_t)N_NODES * DIM * 2);  // 20.48 MB row-major
    unsigned short* xlo  = (unsigned short*)alloc((size_t)N_NODES * DIM * 2);  // 20.48 MB (contiguous)
    unsigned short* wthi = (unsigned short*)alloc((size_t)DIM * DIM * 2);      // W^T row-major
    unsigned short* wtlo = (unsigned short*)alloc((size_t)DIM * DIM * 2);
    unsigned short* hb   = (unsigned short*)alloc((size_t)N_NODES * DIM * 2);  // h in bf16, row-major
    float* es   = (float*)alloc((size_t)N_NODES * 4 * 4);
    float* ed   = (float*)alloc((size_t)N_NODES * 4 * 4);
    int*   cnt  = (int*)alloc((size_t)N_NODES * 4);
    int*   offs = (int*)alloc((size_t)N_NODES * 4);
    int*   curs = (int*)alloc((size_t)N_NODES * 4);
    int*   bkt  = (int*)alloc((size_t)ETOT * 4);
    int*   gcnt   = (int*)alloc(NGRAPH * 4);
    int*   gbeg   = (int*)alloc(NGRAPH * 4);
    int*   gend   = (int*)alloc(NGRAPH * 4);
    // out[n] (41 MB f32) aliases xhi+xlo — dead after gemm3.
    float* outn = (float*)xhi;

    prep_w<<<dim3(16, 16), 256, 0, stream>>>(W2, wthi, wtlo, es, ed, cnt, curs,
                                             gcnt, gbeg, gend);
    prep_xg<<<XBLK + (N_EDGES + 255) / 256, 256, 0, stream>>>(x, xhi, xlo, dstI, batch,
                                                              cnt, gcnt, gbeg, gend);
    gemm3<<<dim3(NCOLT, NROWT), 256, 0, stream>>>(xhi, xlo, wthi, wtlo,
                                                  asrc2, adst2, hb, es, ed);
    scan_k<<<1, 1024, 0, stream>>>(cnt, offs);
    bucket_k<<<(ETOT + 255) / 256, 256, 0, stream>>>(srcI, dstI, offs, curs, bkt);

    aggregate_k<<<N_NODES, 256, 0, stream>>>(hb, es, ed, srcI, cnt, offs, bkt, b2, outn);
    poolfinal_k<<<NGRAPH, 256, 0, stream>>>(outn, gcnt, gbeg, gend, Wr, br, (float*)d_out);
}